// Round 1
// baseline (494.439 us; speedup 1.0000x reference)
//
#include <hip/hip_runtime.h>
#include <math.h>

#define T_LEN   16384          // 4^7
#define NTH     512
#define TPRIME  64
#define NPATH   577            // 1 + 64 + 512
#define INV_T   (1.0f/16384.0f)
#define TWO_PI  6.28318530717958647692f

__device__ __forceinline__ int rev4(int i) {
    int r = 0;
#pragma unroll
    for (int p = 0; p < 7; ++p) { r = (r << 2) | (i & 3); i >>= 2; }
    return r;
}

// ---------------- inverse DIF: natural freq in -> scrambled time out ------
// computes UNSCALED inverse DFT (i.e. N * ifft), in-place in LDS.
__device__ void inv_dif(float2* buf) {
    int lq = 12;
    for (int s = 0; s < 7; ++s, lq -= 2) {
        const int q = 1 << lq;
        __syncthreads();
#pragma unroll
        for (int it = 0; it < (T_LEN / 4) / NTH; ++it) {
            int g = threadIdx.x + it * NTH;
            int j = g & (q - 1);
            int base = ((g >> lq) << (lq + 2)) | j;
            float2 a0 = buf[base];
            float2 a1 = buf[base + q];
            float2 a2 = buf[base + 2 * q];
            float2 a3 = buf[base + 3 * q];
            // s = a0+a1+a2+a3 ; t = a0+i a1-a2-i a3 ; u = a0-a1+a2-a3 ; v = a0-i a1-a2+i a3
            float sr = a0.x + a1.x + a2.x + a3.x, si = a0.y + a1.y + a2.y + a3.y;
            float tr = a0.x - a1.y - a2.x + a3.y, ti = a0.y + a1.x - a2.y - a3.x;
            float ur = a0.x - a1.x + a2.x - a3.x, ui = a0.y - a1.y + a2.y - a3.y;
            float vr = a0.x + a1.y - a2.x - a3.y, vi = a0.y - a1.x - a2.y + a3.x;
            // twiddles w1 = e^{+2pi i j/len}, w2 = w1^2, w3 = w1*w2
            float ang = (float)j * (TWO_PI / (float)(4 << lq));
            float c1, s1; __sincosf(ang, &s1, &c1);
            float c2 = c1 * c1 - s1 * s1, s2 = 2.0f * c1 * s1;
            float c3 = c1 * c2 - s1 * s2, s3 = c1 * s2 + s1 * c2;
            buf[base]         = make_float2(sr, si);
            buf[base + q]     = make_float2(tr * c1 - ti * s1, tr * s1 + ti * c1);
            buf[base + 2 * q] = make_float2(ur * c2 - ui * s2, ur * s2 + ui * c2);
            buf[base + 3 * q] = make_float2(vr * c3 - vi * s3, vr * s3 + vi * c3);
        }
    }
    __syncthreads();
}

// ---------------- forward DIT: scrambled time in -> natural freq out ------
// exact stage-by-stage inverse of inv_dif (x4 per stage) => UNSCALED forward DFT.
__device__ void fwd_dit(float2* buf) {
    int lq = 0;
    for (int s = 0; s < 7; ++s, lq += 2) {
        const int q = 1 << lq;
        __syncthreads();
#pragma unroll
        for (int it = 0; it < (T_LEN / 4) / NTH; ++it) {
            int g = threadIdx.x + it * NTH;
            int j = g & (q - 1);
            int base = ((g >> lq) << (lq + 2)) | j;
            float2 b0 = buf[base];
            float2 b1 = buf[base + q];
            float2 b2 = buf[base + 2 * q];
            float2 b3 = buf[base + 3 * q];
            float ang = (float)j * (TWO_PI / (float)(4 << lq));
            float c1, s1; __sincosf(ang, &s1, &c1);
            float c2 = c1 * c1 - s1 * s1, s2 = 2.0f * c1 * s1;
            float c3 = c1 * c2 - s1 * s2, s3 = c1 * s2 + s1 * c2;
            // un-twiddle: t = b1*e^{-i a1}, u = b2*e^{-i a2}, v = b3*e^{-i a3}
            float trr = b1.x * c1 + b1.y * s1, tii = b1.y * c1 - b1.x * s1;
            float urr = b2.x * c2 + b2.y * s2, uii = b2.y * c2 - b2.x * s2;
            float vrr = b3.x * c3 + b3.y * s3, vii = b3.y * c3 - b3.x * s3;
            float s0r = b0.x, s0i = b0.y;
            // DFT4 rows: [1,1,1,1] [1,-i,-1,i] [1,-1,1,-1] [1,i,-1,-i]
            buf[base]         = make_float2(s0r + trr + urr + vrr, s0i + tii + uii + vii);
            buf[base + q]     = make_float2(s0r + tii - urr - vii, s0i - trr - uii + vrr);
            buf[base + 2 * q] = make_float2(s0r - trr + urr - vrr, s0i - tii + uii - vii);
            buf[base + 3 * q] = make_float2(s0r - tii - urr + vii, s0i + trr - uii - vrr);
        }
    }
    __syncthreads();
}

// fold spectrum with phi into 64 bins, 64-pt inverse DFT, write real part / T.
// MODE 0: buf holds Y in natural order.  MODE 1 (pass A): buf slot rev4(k) = conj(Y[k]).
template<int MODE>
__device__ void fold_lowpass_out(const float2* buf, const float* __restrict__ phi,
                                 float* __restrict__ outp, float2* zpart) {
    const int j  = threadIdx.x & 63;
    const int ls = threadIdx.x >> 6;    // 0..7
    float zr = 0.f, zi = 0.f;
    for (int l = ls * 32; l < ls * 32 + 32; ++l) {
        int k = j + (l << 6);
        float p = phi[k];
        float2 v = (MODE == 0) ? buf[k] : buf[rev4(k)];
        float vy = (MODE == 0) ? v.y : -v.y;
        zr += v.x * p; zi += vy * p;
    }
    zpart[(ls << 6) + j] = make_float2(zr, zi);
    __syncthreads();
    if (threadIdx.x < 64) {
        float2 z = zpart[j];
        for (int p = 1; p < 8; ++p) { z.x += zpart[(p << 6) + j].x; z.y += zpart[(p << 6) + j].y; }
        zpart[j] = z;
    }
    __syncthreads();
    if (threadIdx.x < 64) {
        int m = threadIdx.x;
        float acc = 0.f;
        for (int jj = 0; jj < 64; ++jj) {
            float2 z = zpart[jj];
            float ang = (float)((jj * m) & 63) * (TWO_PI / 64.0f);
            float sn, cs; __sincosf(ang, &sn, &cs);
            acc += z.x * cs - z.y * sn;     // Re(Z * e^{+i ang})
        }
        outp[m] = acc * INV_T;
    }
}

// ---------------- pass A: X = fft(x) (stored natural), S0 -----------------
__global__ __launch_bounds__(NTH) void pass_a(const float* __restrict__ x,
                                              const float* __restrict__ phi,
                                              float2* __restrict__ wsX,
                                              float* __restrict__ out) {
    __shared__ float2 buf[T_LEN];
    __shared__ float2 zpart[512];
    const int b = blockIdx.x;
    const float* xb = x + (size_t)b * T_LEN;
    for (int i = threadIdx.x; i < T_LEN; i += NTH)
        buf[i] = make_float2(xb[i], 0.0f);
    inv_dif(buf);                       // x real => slot i = conj(X[rev4(i)])
    for (int i = threadIdx.x; i < T_LEN; i += NTH) {
        float2 v = buf[i];
        wsX[(size_t)b * T_LEN + rev4(i)] = make_float2(v.x, -v.y);
    }
    fold_lowpass_out<1>(buf, phi, out + (size_t)b * (NPATH * TPRIME), zpart);
}

// ---------------- pass B: per (b,n1): U1h, S1 -----------------------------
__global__ __launch_bounds__(NTH) void pass_b(const float2* __restrict__ wsX,
                                              const float* __restrict__ psi1,
                                              const float* __restrict__ phi,
                                              float2* __restrict__ wsU,
                                              float* __restrict__ out, int store_u) {
    __shared__ float2 buf[T_LEN];
    __shared__ float2 zpart[512];
    const int blk = blockIdx.x;
    const int b = blk >> 6, n1 = blk & 63;
    const float2* Xb = wsX + (size_t)b * T_LEN;
    const float* ps = psi1 + (size_t)n1 * T_LEN;
    for (int i = threadIdx.x; i < T_LEN; i += NTH) {
        float2 v = Xb[i]; float p = ps[i];
        buf[i] = make_float2(v.x * p, v.y * p);
    }
    inv_dif(buf);
    for (int i = threadIdx.x; i < T_LEN; i += NTH) {
        float2 v = buf[i];
        buf[i] = make_float2(sqrtf(v.x * v.x + v.y * v.y) * INV_T, 0.0f);  // U1
    }
    fwd_dit(buf);                       // U1h natural order
    if (store_u) {
        float2* Ub = wsU + (size_t)blk * T_LEN;
        for (int i = threadIdx.x; i < T_LEN; i += NTH) Ub[i] = buf[i];
    }
    fold_lowpass_out<0>(buf, phi,
        out + (size_t)b * (NPATH * TPRIME) + (size_t)(1 + n1) * TPRIME, zpart);
}

// ---------------- pass C: per (b,n1,n2) valid: S2 -------------------------
template<bool STORED>
__global__ __launch_bounds__(NTH) void pass_c(const float2* __restrict__ wsX,
                                              const float2* __restrict__ wsU,
                                              const float* __restrict__ psi1,
                                              const float* __restrict__ psi2,
                                              const float* __restrict__ phi,
                                              float* __restrict__ out) {
    const int blk = blockIdx.x;                 // b*512 + n1*8 + n2
    const int n2 = blk & 7, n1 = (blk >> 3) & 63, b = blk >> 9;
    if (n2 < (n1 >> 3) + 1) return;             // mask: xi2[n2] < xi1[n1]
    __shared__ float2 buf[T_LEN];
    __shared__ float2 zpart[512];
    const float* p2 = psi2 + (size_t)n2 * T_LEN;
    if (STORED) {
        const float2* Ub = wsU + (size_t)((b << 6) | n1) * T_LEN;
        for (int i = threadIdx.x; i < T_LEN; i += NTH) {
            float2 v = Ub[i]; float p = p2[i];
            buf[i] = make_float2(v.x * p, v.y * p);
        }
    } else {
        const float2* Xb = wsX + (size_t)b * T_LEN;
        const float* p1 = psi1 + (size_t)n1 * T_LEN;
        for (int i = threadIdx.x; i < T_LEN; i += NTH) {
            float2 v = Xb[i]; float p = p1[i];
            buf[i] = make_float2(v.x * p, v.y * p);
        }
        inv_dif(buf);
        for (int i = threadIdx.x; i < T_LEN; i += NTH) {
            float2 v = buf[i];
            buf[i] = make_float2(sqrtf(v.x * v.x + v.y * v.y) * INV_T, 0.0f);
        }
        fwd_dit(buf);
        __syncthreads();
        for (int i = threadIdx.x; i < T_LEN; i += NTH) {
            float2 v = buf[i]; float p = p2[i];
            buf[i] = make_float2(v.x * p, v.y * p);
        }
    }
    inv_dif(buf);
    for (int i = threadIdx.x; i < T_LEN; i += NTH) {
        float2 v = buf[i];
        buf[i] = make_float2(sqrtf(v.x * v.x + v.y * v.y) * INV_T, 0.0f);  // U2
    }
    fwd_dit(buf);
    fold_lowpass_out<0>(buf, phi,
        out + (size_t)b * (NPATH * TPRIME) + (size_t)(65 + (n1 << 3) + n2) * TPRIME, zpart);
}

__global__ void zero_out(float* __restrict__ out, int n) {
    int i = blockIdx.x * blockDim.x + threadIdx.x;
    if (i < n) out[i] = 0.0f;
}

extern "C" void kernel_launch(void* const* d_in, const int* in_sizes, int n_in,
                              void* d_out, int out_size, void* d_ws, size_t ws_size,
                              hipStream_t stream) {
    const float* x    = (const float*)d_in[0];
    const float* psi1 = (const float*)d_in[1];
    const float* psi2 = (const float*)d_in[2];
    const float* phi  = (const float*)d_in[3];
    float* out = (float*)d_out;

    const int B = in_sizes[0] / T_LEN;          // 4

    float2* wsX = (float2*)d_ws;
    float2* wsU = (float2*)((char*)d_ws + (size_t)B * T_LEN * sizeof(float2));
    const size_t need = (size_t)B * T_LEN * sizeof(float2)          // X
                      + (size_t)B * 64 * T_LEN * sizeof(float2);    // U1h
    const bool stored = (ws_size >= need);

    const int nout = B * NPATH * TPRIME;
    zero_out<<<(nout + 255) / 256, 256, 0, stream>>>(out, nout);
    pass_a<<<B, NTH, 0, stream>>>(x, phi, wsX, out);
    pass_b<<<B * 64, NTH, 0, stream>>>(wsX, psi1, phi, wsU, out, stored ? 1 : 0);
    if (stored)
        pass_c<true><<<B * 512, NTH, 0, stream>>>(wsX, wsU, psi1, psi2, phi, out);
    else
        pass_c<false><<<B * 512, NTH, 0, stream>>>(wsX, wsU, psi1, psi2, phi, out);
}

// Round 2
// 448.991 us; speedup vs baseline: 1.1012x; 1.1012x over previous
//
#include <hip/hip_runtime.h>
#include <math.h>

#define T_LEN   16384          // 4^7
#define NTH     512
#define TPRIME  64
#define NPATH   577            // 1 + 64 + 512
#define INV_T   (1.0f/16384.0f)
#define TWO_PI  6.28318530717958647692f
#define NW      640            // lowpass kernel half-width (5.5 sigma_t)
#define NH      (NW + 1)

__device__ __forceinline__ int rev4(int i) {
    int r = 0;
#pragma unroll
    for (int p = 0; p < 7; ++p) { r = (r << 2) | (i & 3); i >>= 2; }
    return r;
}
// LDS swizzle for the float2 FFT buffer (involution; spreads strided access)
__device__ __forceinline__ int IDX(int i) {
    return i ^ ((i >> 4) & 15) ^ ((i >> 8) & 15);
}
// LDS swizzle for the real (float) U array (involution)
__device__ __forceinline__ int UIDX(int n) {
    return n ^ ((n >> 5) & 31) ^ ((n >> 10) & 31);
}

// ---------------- inverse DIF: natural freq in -> scrambled time out ------
// computes UNSCALED inverse DFT (i.e. N * ifft), in-place in LDS (swizzled).
__device__ void inv_dif(float2* buf) {
    int lq = 12;
    for (int s = 0; s < 7; ++s, lq -= 2) {
        const int q = 1 << lq;
        __syncthreads();
#pragma unroll
        for (int it = 0; it < (T_LEN / 4) / NTH; ++it) {
            int g = threadIdx.x + it * NTH;
            int j = g & (q - 1);
            int base = ((g >> lq) << (lq + 2)) | j;
            int i0 = IDX(base), i1 = IDX(base + q), i2 = IDX(base + 2 * q), i3 = IDX(base + 3 * q);
            float2 a0 = buf[i0];
            float2 a1 = buf[i1];
            float2 a2 = buf[i2];
            float2 a3 = buf[i3];
            float sr = a0.x + a1.x + a2.x + a3.x, si = a0.y + a1.y + a2.y + a3.y;
            float tr = a0.x - a1.y - a2.x + a3.y, ti = a0.y + a1.x - a2.y - a3.x;
            float ur = a0.x - a1.x + a2.x - a3.x, ui = a0.y - a1.y + a2.y - a3.y;
            float vr = a0.x + a1.y - a2.x - a3.y, vi = a0.y - a1.x - a2.y + a3.x;
            float ang = (float)j * (TWO_PI / (float)(4 << lq));
            float c1, s1; __sincosf(ang, &s1, &c1);
            float c2 = c1 * c1 - s1 * s1, s2 = 2.0f * c1 * s1;
            float c3 = c1 * c2 - s1 * s2, s3 = c1 * s2 + s1 * c2;
            buf[i0] = make_float2(sr, si);
            buf[i1] = make_float2(tr * c1 - ti * s1, tr * s1 + ti * c1);
            buf[i2] = make_float2(ur * c2 - ui * s2, ur * s2 + ui * c2);
            buf[i3] = make_float2(vr * c3 - vi * s3, vr * s3 + vi * c3);
        }
    }
    __syncthreads();
}

// ---------------- forward DIT: scrambled time in -> natural freq out ------
__device__ void fwd_dit(float2* buf) {
    int lq = 0;
    for (int s = 0; s < 7; ++s, lq += 2) {
        const int q = 1 << lq;
        __syncthreads();
#pragma unroll
        for (int it = 0; it < (T_LEN / 4) / NTH; ++it) {
            int g = threadIdx.x + it * NTH;
            int j = g & (q - 1);
            int base = ((g >> lq) << (lq + 2)) | j;
            int i0 = IDX(base), i1 = IDX(base + q), i2 = IDX(base + 2 * q), i3 = IDX(base + 3 * q);
            float2 b0 = buf[i0];
            float2 b1 = buf[i1];
            float2 b2 = buf[i2];
            float2 b3 = buf[i3];
            float ang = (float)j * (TWO_PI / (float)(4 << lq));
            float c1, s1; __sincosf(ang, &s1, &c1);
            float c2 = c1 * c1 - s1 * s1, s2 = 2.0f * c1 * s1;
            float c3 = c1 * c2 - s1 * s2, s3 = c1 * s2 + s1 * c2;
            float trr = b1.x * c1 + b1.y * s1, tii = b1.y * c1 - b1.x * s1;
            float urr = b2.x * c2 + b2.y * s2, uii = b2.y * c2 - b2.x * s2;
            float vrr = b3.x * c3 + b3.y * s3, vii = b3.y * c3 - b3.x * s3;
            float s0r = b0.x, s0i = b0.y;
            buf[i0] = make_float2(s0r + trr + urr + vrr, s0i + tii + uii + vii);
            buf[i1] = make_float2(s0r + tii - urr - vii, s0i - trr - uii + vrr);
            buf[i2] = make_float2(s0r - trr + urr - vrr, s0i - tii + uii - vii);
            buf[i3] = make_float2(s0r - tii - urr + vii, s0i + trr - uii - vrr);
        }
    }
    __syncthreads();
}

// ------- time-domain lowpass + subsample: out[m] = sum_e h[|e|] U[(256m+e)%T]
// SRC 0: buf natural order (.x);  SRC 1: buf scrambled (.x at rev4);  SRC 2: uf swizzled real
template<int SRC>
__device__ void lowpass_conv(const float2* buf, const float* uf,
                             const float* hl, float* __restrict__ outp) {
    const int m = threadIdx.x >> 3;
    const int s = threadIdx.x & 7;
    const int c = m << 8;
    float acc = 0.f;
    for (int e = -NW + s; e <= NW; e += 8) {
        int n = (c + e) & (T_LEN - 1);
        float u;
        if (SRC == 0)       u = buf[IDX(n)].x;
        else if (SRC == 1)  u = buf[IDX(rev4(n))].x;
        else                u = uf[UIDX(n)];
        int a = e < 0 ? -e : e;
        acc += hl[a] * u;
    }
    acc += __shfl_xor(acc, 1);
    acc += __shfl_xor(acc, 2);
    acc += __shfl_xor(acc, 4);
    if (s == 0) outp[m] = acc;
}

// ---------- h precompute: h[d] = (1/T) sum_k phi[k] cos(2*pi*k*d/T) --------
__global__ __launch_bounds__(256) void hconv(const float* __restrict__ phi,
                                             float* __restrict__ hws) {
    __shared__ float red[256];
    const int d = blockIdx.x;                 // 0..NW
    float p = 0.f;
    for (int k = threadIdx.x; k < T_LEN; k += 256) {
        int r = (k * d) & (T_LEN - 1);        // exact angle reduction
        p += phi[k] * __cosf((float)r * (TWO_PI / (float)T_LEN));
    }
    red[threadIdx.x] = p;
    __syncthreads();
    for (int w = 128; w >= 1; w >>= 1) {
        if (threadIdx.x < w) red[threadIdx.x] += red[threadIdx.x + w];
        __syncthreads();
    }
    if (threadIdx.x == 0) hws[d] = red[0] * INV_T;
}

// ---------------- pass A: S0 (conv) + X = fft(x) stored natural -----------
__global__ __launch_bounds__(NTH) void pass_a(const float* __restrict__ x,
                                              const float* __restrict__ hws,
                                              float2* __restrict__ wsX,
                                              float* __restrict__ out) {
    __shared__ float2 buf[T_LEN];
    __shared__ float hl[NH];
    const int b = blockIdx.x;
    const float* xb = x + (size_t)b * T_LEN;
    for (int i = threadIdx.x; i < NH; i += NTH) hl[i] = hws[i];
    for (int i = threadIdx.x; i < T_LEN; i += NTH)
        buf[IDX(i)] = make_float2(xb[i], 0.0f);
    __syncthreads();
    lowpass_conv<0>(buf, nullptr, hl, out + (size_t)b * (NPATH * TPRIME));
    inv_dif(buf);                       // slot i = conj(X[rev4(i)])
    for (int i = threadIdx.x; i < T_LEN; i += NTH) {
        float2 v = buf[IDX(i)];
        wsX[(size_t)b * T_LEN + rev4(i)] = make_float2(v.x, -v.y);
    }
}

// ---------------- pass B: per (b,n1): U1, S1 (conv), U1h ------------------
__global__ __launch_bounds__(NTH) void pass_b(const float2* __restrict__ wsX,
                                              const float* __restrict__ psi1,
                                              const float* __restrict__ hws,
                                              float2* __restrict__ wsU,
                                              float* __restrict__ out, int store_u) {
    __shared__ float2 buf[T_LEN];
    __shared__ float hl[NH];
    const int blk = blockIdx.x;
    const int b = blk >> 6, n1 = blk & 63;
    for (int i = threadIdx.x; i < NH; i += NTH) hl[i] = hws[i];
    const float2* Xb = wsX + (size_t)b * T_LEN;
    const float* ps = psi1 + (size_t)n1 * T_LEN;
    for (int i = threadIdx.x; i < T_LEN; i += NTH) {
        float2 v = Xb[i]; float p = ps[i];
        buf[IDX(i)] = make_float2(v.x * p, v.y * p);
    }
    inv_dif(buf);
    for (int i = threadIdx.x; i < T_LEN; i += NTH) {
        int ii = IDX(i);
        float2 v = buf[ii];
        buf[ii] = make_float2(sqrtf(v.x * v.x + v.y * v.y) * INV_T, 0.0f);  // U1
    }
    __syncthreads();
    lowpass_conv<1>(buf, nullptr, hl,
        out + (size_t)b * (NPATH * TPRIME) + (size_t)(1 + n1) * TPRIME);
    fwd_dit(buf);                       // U1h natural order (swizzled slots)
    if (store_u) {
        float2* Ub = wsU + (size_t)blk * T_LEN;
        for (int i = threadIdx.x; i < T_LEN; i += NTH) Ub[i] = buf[IDX(i)];
    }
}

// ---------------- pass C: per (b,n1,n2) valid: U2, S2 (conv) --------------
template<bool STORED>
__global__ __launch_bounds__(NTH) void pass_c(const float2* __restrict__ wsX,
                                              const float2* __restrict__ wsU,
                                              const float* __restrict__ psi1,
                                              const float* __restrict__ psi2,
                                              const float* __restrict__ hws,
                                              float* __restrict__ out) {
    const int blk = blockIdx.x;                 // b*512 + n1*8 + n2
    const int n2 = blk & 7, n1 = (blk >> 3) & 63, b = blk >> 9;
    if (n2 < (n1 >> 3) + 1) return;             // mask: xi2[n2] < xi1[n1]
    __shared__ float2 buf[T_LEN];
    __shared__ float hl[NH];
    for (int i = threadIdx.x; i < NH; i += NTH) hl[i] = hws[i];
    const float* p2 = psi2 + (size_t)n2 * T_LEN;
    if (STORED) {
        const float2* Ub = wsU + (size_t)((b << 6) | n1) * T_LEN;
        for (int i = threadIdx.x; i < T_LEN; i += NTH) {
            float2 v = Ub[i]; float p = p2[i];
            buf[IDX(i)] = make_float2(v.x * p, v.y * p);
        }
    } else {
        const float2* Xb = wsX + (size_t)b * T_LEN;
        const float* p1 = psi1 + (size_t)n1 * T_LEN;
        for (int i = threadIdx.x; i < T_LEN; i += NTH) {
            float2 v = Xb[i]; float p = p1[i];
            buf[IDX(i)] = make_float2(v.x * p, v.y * p);
        }
        inv_dif(buf);
        for (int i = threadIdx.x; i < T_LEN; i += NTH) {
            int ii = IDX(i);
            float2 v = buf[ii];
            buf[ii] = make_float2(sqrtf(v.x * v.x + v.y * v.y) * INV_T, 0.0f);
        }
        fwd_dit(buf);
        __syncthreads();
        for (int i = threadIdx.x; i < T_LEN; i += NTH) {
            int ii = IDX(i);
            float2 v = buf[ii]; float p = p2[i];
            buf[ii] = make_float2(v.x * p, v.y * p);
        }
    }
    inv_dif(buf);
    // modulus -> registers -> scatter to natural-time real array (aliased)
    float mag[32];
#pragma unroll
    for (int k = 0; k < 32; ++k) {
        int i = threadIdx.x + k * NTH;
        float2 v = buf[IDX(i)];
        mag[k] = sqrtf(v.x * v.x + v.y * v.y) * INV_T;   // U2 at time rev4(i)
    }
    __syncthreads();
    float* uf = (float*)buf;
#pragma unroll
    for (int k = 0; k < 32; ++k) {
        int i = threadIdx.x + k * NTH;
        uf[UIDX(rev4(i))] = mag[k];
    }
    __syncthreads();
    lowpass_conv<2>(nullptr, uf, hl,
        out + (size_t)b * (NPATH * TPRIME) + (size_t)(65 + (n1 << 3) + n2) * TPRIME);
}

__global__ void zero_out(float* __restrict__ out, int n) {
    int i = blockIdx.x * blockDim.x + threadIdx.x;
    if (i < n) out[i] = 0.0f;
}

extern "C" void kernel_launch(void* const* d_in, const int* in_sizes, int n_in,
                              void* d_out, int out_size, void* d_ws, size_t ws_size,
                              hipStream_t stream) {
    const float* x    = (const float*)d_in[0];
    const float* psi1 = (const float*)d_in[1];
    const float* psi2 = (const float*)d_in[2];
    const float* phi  = (const float*)d_in[3];
    float* out = (float*)d_out;

    const int B = in_sizes[0] / T_LEN;          // 4

    float*  hws = (float*)d_ws;                               // NH floats (pad 4 KiB)
    float2* wsX = (float2*)((char*)d_ws + 4096);
    float2* wsU = (float2*)((char*)d_ws + 4096 + (size_t)B * T_LEN * sizeof(float2));
    const size_t need = 4096 + (size_t)B * T_LEN * sizeof(float2)
                      + (size_t)B * 64 * T_LEN * sizeof(float2);
    const bool stored = (ws_size >= need);

    const int nout = B * NPATH * TPRIME;
    zero_out<<<(nout + 255) / 256, 256, 0, stream>>>(out, nout);
    hconv<<<NH, 256, 0, stream>>>(phi, hws);
    pass_a<<<B, NTH, 0, stream>>>(x, hws, wsX, out);
    pass_b<<<B * 64, NTH, 0, stream>>>(wsX, psi1, hws, wsU, out, stored ? 1 : 0);
    if (stored)
        pass_c<true><<<B * 512, NTH, 0, stream>>>(wsX, wsU, psi1, psi2, hws, out);
    else
        pass_c<false><<<B * 512, NTH, 0, stream>>>(wsX, wsU, psi1, psi2, hws, out);
}

// Round 3
// 429.224 us; speedup vs baseline: 1.1519x; 1.0461x over previous
//
#include <hip/hip_runtime.h>
#include <math.h>

#define T_LEN   16384          // 4^7
#define NTH     512
#define TPRIME  64
#define NPATH   577            // 1 + 64 + 512
#define INV_T   (1.0f/16384.0f)
#define TWO_PI  6.28318530717958647692f
#define NW      640            // lowpass kernel half-width (5.5 sigma_t)
#define NH      (NW + 1)
#define C8C     0.92387953251128675613f   // cos(pi/8)
#define C8S     0.38268343236508977173f   // sin(pi/8)

__device__ __forceinline__ int rev4(int i) {
    int r = 0;
#pragma unroll
    for (int p = 0; p < 7; ++p) { r = (r << 2) | (i & 3); i >>= 2; }
    return r;
}
// LDS swizzle for the float2 FFT buffer (involution)
__device__ __forceinline__ int IDX(int i) {
    return i ^ ((i >> 4) & 15) ^ ((i >> 8) & 15);
}
// LDS swizzle for the real (float) U array (involution)
__device__ __forceinline__ int UIDX(int n) {
    return n ^ ((n >> 5) & 31) ^ ((n >> 10) & 31);
}

// radix-4 inverse butterfly (e^{+i}), applies twiddles w1=(c1,s1), w2=w1^2, w3=w1^3
__device__ __forceinline__ void inv_bf4(float2& A0, float2& A1, float2& A2, float2& A3,
                                        float c1, float s1) {
    float sr = A0.x + A1.x + A2.x + A3.x, si = A0.y + A1.y + A2.y + A3.y;
    float tr = A0.x - A1.y - A2.x + A3.y, ti = A0.y + A1.x - A2.y - A3.x;
    float ur = A0.x - A1.x + A2.x - A3.x, ui = A0.y - A1.y + A2.y - A3.y;
    float vr = A0.x + A1.y - A2.x - A3.y, vi = A0.y - A1.x - A2.y + A3.x;
    float c2 = c1*c1 - s1*s1, s2 = 2.f*c1*s1;
    float c3 = c1*c2 - s1*s2, s3 = c1*s2 + s1*c2;
    A0 = make_float2(sr, si);
    A1 = make_float2(tr*c1 - ti*s1, tr*s1 + ti*c1);
    A2 = make_float2(ur*c2 - ui*s2, ur*s2 + ui*c2);
    A3 = make_float2(vr*c3 - vi*s3, vr*s3 + vi*c3);
}

// radix-4 forward butterfly: un-twiddle by conj(w) then DFT4
__device__ __forceinline__ void fwd_bf4(float2& B0, float2& B1, float2& B2, float2& B3,
                                        float c1, float s1) {
    float c2 = c1*c1 - s1*s1, s2 = 2.f*c1*s1;
    float c3 = c1*c2 - s1*s2, s3 = c1*s2 + s1*c2;
    float trr = B1.x*c1 + B1.y*s1, tii = B1.y*c1 - B1.x*s1;
    float urr = B2.x*c2 + B2.y*s2, uii = B2.y*c2 - B2.x*s2;
    float vrr = B3.x*c3 + B3.y*s3, vii = B3.y*c3 - B3.x*s3;
    float s0r = B0.x, s0i = B0.y;
    B0 = make_float2(s0r + trr + urr + vrr, s0i + tii + uii + vii);
    B1 = make_float2(s0r + tii - urr - vii, s0i - trr - uii + vrr);
    B2 = make_float2(s0r - trr + urr - vrr, s0i - tii + uii - vii);
    B3 = make_float2(s0r - tii - urr + vii, s0i + trr - uii - vrr);
}

// two merged inverse DIF radix-4 stages on one 16-point register group.
// Q = span of first stage's q. v[4r+rp] = element at base + r*Q + rp*(Q/4).
template<int Q>
__device__ __forceinline__ void inv_group16(float2* v, int jp) {
    float a0 = (float)jp * (TWO_PI / (float)(4 * Q));
    float cw, sw; __sincosf(a0, &sw, &cw);
    float c = cw, s = sw;
#pragma unroll
    for (int rp = 0; rp < 4; ++rp) {                 // stage s: angle jp*th + rp*pi/8
        inv_bf4(v[rp], v[4+rp], v[8+rp], v[12+rp], c, s);
        float cn = c*C8C - s*C8S, sn = c*C8S + s*C8C;
        c = cn; s = sn;
    }
    float b0 = (float)jp * (TWO_PI / (float)Q);      // stage s+1: angle jp*2pi/Q
    float cb, sb; __sincosf(b0, &sb, &cb);
#pragma unroll
    for (int r = 0; r < 4; ++r)
        inv_bf4(v[4*r], v[4*r+1], v[4*r+2], v[4*r+3], cb, sb);
}

// two merged forward DIT radix-4 stages; QA = first (smaller) stage q.
// v[4r+rp] = element at base + r*(4*QA) + rp*QA.
template<int QA>
__device__ __forceinline__ void fwd_group16(float2* v, int jp) {
    float aA = (float)jp * (TWO_PI / (float)(4 * QA));
    float cA, sA; __sincosf(aA, &sA, &cA);
#pragma unroll
    for (int r = 0; r < 4; ++r)
        fwd_bf4(v[4*r], v[4*r+1], v[4*r+2], v[4*r+3], cA, sA);
    float aB = (float)jp * (TWO_PI / (float)(16 * QA));
    float cB, sB; __sincosf(aB, &sB, &cB);
    float c = cB, s = sB;
#pragma unroll
    for (int rp = 0; rp < 4; ++rp) {
        fwd_bf4(v[rp], v[4+rp], v[8+rp], v[12+rp], c, s);
        float cn = c*C8C - s*C8S, sn = c*C8S + s*C8C;
        c = cn; s = sn;
    }
}

// merged inverse pass, LDS -> LDS.  LQ in {12, 8, 4}.
template<int LQ>
__device__ void inv_pass16(float2* buf) {
    const int q = 1 << LQ, qp = q >> 2;
    __syncthreads();
    float2 v[2][16];
#pragma unroll
    for (int it = 0; it < 2; ++it) {
        int g2 = threadIdx.x + it * NTH;
        int jp = g2 & (qp - 1);
        int base = ((g2 >> (LQ - 2)) << (LQ + 2)) | jp;
#pragma unroll
        for (int r = 0; r < 4; ++r)
#pragma unroll
            for (int rp = 0; rp < 4; ++rp)
                v[it][4*r+rp] = buf[IDX(base + r*q + rp*qp)];
    }
#pragma unroll
    for (int it = 0; it < 2; ++it) {
        int g2 = threadIdx.x + it * NTH;
        int jp = g2 & (qp - 1);
        int base = ((g2 >> (LQ - 2)) << (LQ + 2)) | jp;
        inv_group16<(1 << LQ)>(v[it], jp);
#pragma unroll
        for (int r = 0; r < 4; ++r)
#pragma unroll
            for (int rp = 0; rp < 4; ++rp)
                buf[IDX(base + r*q + rp*qp)] = v[it][4*r+rp];
    }
}

// merged inverse pass 0 (LQ=12) reading (src * filt) straight from global.
__device__ void inv_pass16_g(const float2* __restrict__ src, const float* __restrict__ filt,
                             float2* buf) {
    float2 v[2][16];
#pragma unroll
    for (int it = 0; it < 2; ++it) {
        int jp = threadIdx.x + it * NTH;
#pragma unroll
        for (int r = 0; r < 4; ++r)
#pragma unroll
            for (int rp = 0; rp < 4; ++rp) {
                int i = jp + r*4096 + rp*1024;
                float2 a = src[i]; float p = filt[i];
                v[it][4*r+rp] = make_float2(a.x*p, a.y*p);
            }
    }
#pragma unroll
    for (int it = 0; it < 2; ++it) {
        int jp = threadIdx.x + it * NTH;
        inv_group16<4096>(v[it], jp);
#pragma unroll
        for (int r = 0; r < 4; ++r)
#pragma unroll
            for (int rp = 0; rp < 4; ++rp)
                buf[IDX(jp + r*4096 + rp*1024)] = v[it][4*r+rp];
    }
}

// final inverse radix-4 (lq=0, twiddle=1): generic float2 write-back
__device__ void inv_last(float2* buf) {
    __syncthreads();
#pragma unroll
    for (int it = 0; it < 8; ++it) {
        int base = (threadIdx.x + it * NTH) << 2;
        float2 a0 = buf[IDX(base)], a1 = buf[IDX(base+1)], a2 = buf[IDX(base+2)], a3 = buf[IDX(base+3)];
        inv_bf4(a0, a1, a2, a3, 1.0f, 0.0f);
        buf[IDX(base)] = a0; buf[IDX(base+1)] = a1; buf[IDX(base+2)] = a2; buf[IDX(base+3)] = a3;
    }
    __syncthreads();
}

// final inverse radix-4 fused with modulus: writes float2(|.|/T, 0)
__device__ void inv_last_mod(float2* buf) {
    __syncthreads();
#pragma unroll
    for (int it = 0; it < 8; ++it) {
        int base = (threadIdx.x + it * NTH) << 2;
        float2 a0 = buf[IDX(base)], a1 = buf[IDX(base+1)], a2 = buf[IDX(base+2)], a3 = buf[IDX(base+3)];
        inv_bf4(a0, a1, a2, a3, 1.0f, 0.0f);
        buf[IDX(base)]   = make_float2(sqrtf(a0.x*a0.x + a0.y*a0.y) * INV_T, 0.f);
        buf[IDX(base+1)] = make_float2(sqrtf(a1.x*a1.x + a1.y*a1.y) * INV_T, 0.f);
        buf[IDX(base+2)] = make_float2(sqrtf(a2.x*a2.x + a2.y*a2.y) * INV_T, 0.f);
        buf[IDX(base+3)] = make_float2(sqrtf(a3.x*a3.x + a3.y*a3.y) * INV_T, 0.f);
    }
    __syncthreads();
}

// final inverse radix-4 fused with modulus + scatter to natural-time real array
__device__ void inv_last_scatter(float2* buf) {
    __syncthreads();
    float mag[32];
#pragma unroll
    for (int it = 0; it < 8; ++it) {
        int base = (threadIdx.x + it * NTH) << 2;
        float2 a0 = buf[IDX(base)], a1 = buf[IDX(base+1)], a2 = buf[IDX(base+2)], a3 = buf[IDX(base+3)];
        inv_bf4(a0, a1, a2, a3, 1.0f, 0.0f);
        mag[4*it+0] = sqrtf(a0.x*a0.x + a0.y*a0.y) * INV_T;
        mag[4*it+1] = sqrtf(a1.x*a1.x + a1.y*a1.y) * INV_T;
        mag[4*it+2] = sqrtf(a2.x*a2.x + a2.y*a2.y) * INV_T;
        mag[4*it+3] = sqrtf(a3.x*a3.x + a3.y*a3.y) * INV_T;
    }
    __syncthreads();
    float* uf = (float*)buf;
#pragma unroll
    for (int it = 0; it < 8; ++it) {
        int base = (threadIdx.x + it * NTH) << 2;
        int rb = rev4(base);            // rev4(base+k) = rb + k*4096 (low digit of base is 0)
#pragma unroll
        for (int k = 0; k < 4; ++k)
            uf[UIDX(rb + k*4096)] = mag[4*it+k];
    }
    __syncthreads();
}

// forward first radix-4 pass (lq=0, twiddle=1)
__device__ void fwd_first(float2* buf) {
    __syncthreads();
#pragma unroll
    for (int it = 0; it < 8; ++it) {
        int base = (threadIdx.x + it * NTH) << 2;
        float2 a0 = buf[IDX(base)], a1 = buf[IDX(base+1)], a2 = buf[IDX(base+2)], a3 = buf[IDX(base+3)];
        fwd_bf4(a0, a1, a2, a3, 1.0f, 0.0f);
        buf[IDX(base)] = a0; buf[IDX(base+1)] = a1; buf[IDX(base+2)] = a2; buf[IDX(base+3)] = a3;
    }
}

// merged forward pass, LDS -> LDS.  LQA in {2, 6, 10}.
template<int LQA>
__device__ void fwd_pass16(float2* buf) {
    const int qA = 1 << LQA, qB = 4 * qA;
    __syncthreads();
    float2 v[2][16];
#pragma unroll
    for (int it = 0; it < 2; ++it) {
        int g2 = threadIdx.x + it * NTH;
        int jp = g2 & (qA - 1);
        int base = ((g2 >> LQA) << (LQA + 4)) | jp;
#pragma unroll
        for (int r = 0; r < 4; ++r)
#pragma unroll
            for (int rp = 0; rp < 4; ++rp)
                v[it][4*r+rp] = buf[IDX(base + r*qB + rp*qA)];
    }
#pragma unroll
    for (int it = 0; it < 2; ++it) {
        int g2 = threadIdx.x + it * NTH;
        int jp = g2 & (qA - 1);
        int base = ((g2 >> LQA) << (LQA + 4)) | jp;
        fwd_group16<(1 << LQA)>(v[it], jp);
#pragma unroll
        for (int r = 0; r < 4; ++r)
#pragma unroll
            for (int rp = 0; rp < 4; ++rp)
                buf[IDX(base + r*qB + rp*qA)] = v[it][4*r+rp];
    }
}

// last forward merged pass (LQA=10) writing natural-order result to GLOBAL only
__device__ void fwd_last_store(float2* buf, float2* __restrict__ gout) {
    __syncthreads();
    float2 v[2][16];
#pragma unroll
    for (int it = 0; it < 2; ++it) {
        int jp = threadIdx.x + it * NTH;
#pragma unroll
        for (int r = 0; r < 4; ++r)
#pragma unroll
            for (int rp = 0; rp < 4; ++rp)
                v[it][4*r+rp] = buf[IDX(jp + r*4096 + rp*1024)];
    }
#pragma unroll
    for (int it = 0; it < 2; ++it) {
        int jp = threadIdx.x + it * NTH;
        fwd_group16<1024>(v[it], jp);
#pragma unroll
        for (int r = 0; r < 4; ++r)
#pragma unroll
            for (int rp = 0; rp < 4; ++rp)
                gout[jp + r*4096 + rp*1024] = v[it][4*r+rp];
    }
}

// ------- time-domain lowpass + subsample: out[m] = sum_e h[|e|] U[(256m+e)%T]
template<int SRC>
__device__ void lowpass_conv(const float2* buf, const float* uf,
                             const float* hl, float* __restrict__ outp) {
    const int m = threadIdx.x >> 3;
    const int s = threadIdx.x & 7;
    const int c = m << 8;
    float acc = 0.f;
    for (int e = -NW + s; e <= NW; e += 8) {
        int n = (c + e) & (T_LEN - 1);
        float u;
        if (SRC == 0)       u = buf[IDX(n)].x;
        else if (SRC == 1)  u = buf[IDX(rev4(n))].x;
        else                u = uf[UIDX(n)];
        int a = e < 0 ? -e : e;
        acc += hl[a] * u;
    }
    acc += __shfl_xor(acc, 1);
    acc += __shfl_xor(acc, 2);
    acc += __shfl_xor(acc, 4);
    if (s == 0) outp[m] = acc;
}

// ---------- h precompute: h[d] = (1/T) sum_k phi[k] cos(2*pi*k*d/T) --------
__global__ __launch_bounds__(256) void hconv(const float* __restrict__ phi,
                                             float* __restrict__ hws) {
    __shared__ float red[256];
    const int d = blockIdx.x;                 // 0..NW
    float p = 0.f;
    for (int k = threadIdx.x; k < T_LEN; k += 256) {
        int r = (k * d) & (T_LEN - 1);        // exact angle reduction
        p += phi[k] * __cosf((float)r * (TWO_PI / (float)T_LEN));
    }
    red[threadIdx.x] = p;
    __syncthreads();
    for (int w = 128; w >= 1; w >>= 1) {
        if (threadIdx.x < w) red[threadIdx.x] += red[threadIdx.x + w];
        __syncthreads();
    }
    if (threadIdx.x == 0) hws[d] = red[0] * INV_T;
}

// ---------------- pass A: S0 (conv) + X = fft(x) stored natural -----------
__global__ __launch_bounds__(NTH) void pass_a(const float* __restrict__ x,
                                              const float* __restrict__ hws,
                                              float2* __restrict__ wsX,
                                              float* __restrict__ out) {
    __shared__ float2 buf[T_LEN];
    __shared__ float hl[NH];
    const int b = blockIdx.x;
    const float* xb = x + (size_t)b * T_LEN;
    for (int i = threadIdx.x; i < NH; i += NTH) hl[i] = hws[i];
    for (int i = threadIdx.x; i < T_LEN; i += NTH)
        buf[IDX(i)] = make_float2(xb[i], 0.0f);
    __syncthreads();
    lowpass_conv<0>(buf, nullptr, hl, out + (size_t)b * (NPATH * TPRIME));
    inv_pass16<12>(buf);
    inv_pass16<8>(buf);
    inv_pass16<4>(buf);
    inv_last(buf);                      // slot i = conj(X[rev4(i)])
    for (int i = threadIdx.x; i < T_LEN; i += NTH) {
        float2 v = buf[IDX(i)];
        wsX[(size_t)b * T_LEN + rev4(i)] = make_float2(v.x, -v.y);
    }
}

// ---------------- pass B: per (b,n1): U1, S1 (conv), U1h ------------------
__global__ __launch_bounds__(NTH) void pass_b(const float2* __restrict__ wsX,
                                              const float* __restrict__ psi1,
                                              const float* __restrict__ hws,
                                              float2* __restrict__ wsU,
                                              float* __restrict__ out, int store_u) {
    __shared__ float2 buf[T_LEN];
    __shared__ float hl[NH];
    const int blk = blockIdx.x;
    const int b = blk >> 6, n1 = blk & 63;
    for (int i = threadIdx.x; i < NH; i += NTH) hl[i] = hws[i];
    inv_pass16_g(wsX + (size_t)b * T_LEN, psi1 + (size_t)n1 * T_LEN, buf);
    inv_pass16<8>(buf);
    inv_pass16<4>(buf);
    inv_last_mod(buf);                  // U1 as float2(mag,0), scrambled time
    lowpass_conv<1>(buf, nullptr, hl,
        out + (size_t)b * (NPATH * TPRIME) + (size_t)(1 + n1) * TPRIME);
    if (store_u) {
        fwd_first(buf);                 // leading sync orders conv reads before overwrite
        fwd_pass16<2>(buf);
        fwd_pass16<6>(buf);
        fwd_last_store(buf, wsU + (size_t)blk * T_LEN);
    }
}

// ---------------- pass C: per (b,n1,n2) valid: U2, S2 (conv) --------------
template<bool STORED>
__global__ __launch_bounds__(NTH) void pass_c(const float2* __restrict__ wsX,
                                              const float2* __restrict__ wsU,
                                              const float* __restrict__ psi1,
                                              const float* __restrict__ psi2,
                                              const float* __restrict__ hws,
                                              float* __restrict__ out) {
    const int blk = blockIdx.x;                 // b*512 + n1*8 + n2
    const int n2 = blk & 7, n1 = (blk >> 3) & 63, b = blk >> 9;
    if (n2 < (n1 >> 3) + 1) return;             // mask: xi2[n2] < xi1[n1]
    __shared__ float2 buf[T_LEN];
    __shared__ float hl[NH];
    for (int i = threadIdx.x; i < NH; i += NTH) hl[i] = hws[i];
    const float* p2 = psi2 + (size_t)n2 * T_LEN;
    if (STORED) {
        inv_pass16_g(wsU + (size_t)((b << 6) | n1) * T_LEN, p2, buf);
    } else {
        inv_pass16_g(wsX + (size_t)b * T_LEN, psi1 + (size_t)n1 * T_LEN, buf);
        inv_pass16<8>(buf);
        inv_pass16<4>(buf);
        inv_last_mod(buf);
        fwd_first(buf);
        fwd_pass16<2>(buf);
        fwd_pass16<6>(buf);
        fwd_pass16<10>(buf);
        __syncthreads();
        for (int i = threadIdx.x; i < T_LEN; i += NTH) {
            int ii = IDX(i);
            float2 v = buf[ii]; float p = p2[i];
            buf[ii] = make_float2(v.x * p, v.y * p);
        }
        inv_pass16<12>(buf);
    }
    inv_pass16<8>(buf);
    inv_pass16<4>(buf);
    inv_last_scatter(buf);              // U2 scattered to natural-time real array
    lowpass_conv<2>(nullptr, (const float*)buf, hl,
        out + (size_t)b * (NPATH * TPRIME) + (size_t)(65 + (n1 << 3) + n2) * TPRIME);
}

__global__ void zero_out(float* __restrict__ out, int n) {
    int i = blockIdx.x * blockDim.x + threadIdx.x;
    if (i < n) out[i] = 0.0f;
}

extern "C" void kernel_launch(void* const* d_in, const int* in_sizes, int n_in,
                              void* d_out, int out_size, void* d_ws, size_t ws_size,
                              hipStream_t stream) {
    const float* x    = (const float*)d_in[0];
    const float* psi1 = (const float*)d_in[1];
    const float* psi2 = (const float*)d_in[2];
    const float* phi  = (const float*)d_in[3];
    float* out = (float*)d_out;

    const int B = in_sizes[0] / T_LEN;          // 4

    float*  hws = (float*)d_ws;                               // NH floats (pad 4 KiB)
    float2* wsX = (float2*)((char*)d_ws + 4096);
    float2* wsU = (float2*)((char*)d_ws + 4096 + (size_t)B * T_LEN * sizeof(float2));
    const size_t need = 4096 + (size_t)B * T_LEN * sizeof(float2)
                      + (size_t)B * 64 * T_LEN * sizeof(float2);
    const bool stored = (ws_size >= need);

    const int nout = B * NPATH * TPRIME;
    zero_out<<<(nout + 255) / 256, 256, 0, stream>>>(out, nout);
    hconv<<<NH, 256, 0, stream>>>(phi, hws);
    pass_a<<<B, NTH, 0, stream>>>(x, hws, wsX, out);
    pass_b<<<B * 64, NTH, 0, stream>>>(wsX, psi1, hws, wsU, out, stored ? 1 : 0);
    if (stored)
        pass_c<true><<<B * 512, NTH, 0, stream>>>(wsX, wsU, psi1, psi2, hws, out);
    else
        pass_c<false><<<B * 512, NTH, 0, stream>>>(wsX, wsU, psi1, psi2, hws, out);
}